// Round 1
// baseline (2362.761 us; speedup 1.0000x reference)
//
#include <hip/hip_runtime.h>

#define N_NODES 100000
#define N_EDGES 1600000
#define B_GRAPHS 64
#define BN_EPS 1e-5f

// ---------------- degree ----------------
__global__ void deg_kernel(const int* __restrict__ col, float* __restrict__ deg) {
    int t = blockIdx.x * blockDim.x + threadIdx.x;
    if (t < N_EDGES) atomicAdd(&deg[col[t]], 1.0f);
}

__global__ void dis_kernel(float* __restrict__ deg) {
    int i = blockIdx.x * blockDim.x + threadIdx.x;
    if (i < N_NODES) deg[i] = rsqrtf(deg[i] + 1.0f);  // +1 = self-loop
}

// ---------------- dense per-node matmul: xw[i][o] = sum_k h[i][k] * W[k][o] ----------------
template <int IN, int OUT>
__global__ void matmul_kernel(const float* __restrict__ h, const float* __restrict__ W,
                              float* __restrict__ xw) {
    __shared__ float Ws[IN * OUT];
    for (int k = threadIdx.x; k < IN * OUT; k += blockDim.x) Ws[k] = W[k];
    __syncthreads();
    int t = blockIdx.x * blockDim.x + threadIdx.x;
    const int total = N_NODES * OUT;
    if (t >= total) return;
    int i = t / OUT, o = t % OUT;
    float acc = 0.f;
#pragma unroll
    for (int k = 0; k < IN; k++) acc += h[i * IN + k] * Ws[k * OUT + o];
    xw[t] = acc;
}

// ---------------- edge aggregation: agg[col][f] += xw[row][f] * dis[row]*dis[col] ----------------
template <int F>
__global__ void agg_kernel(const int* __restrict__ row, const int* __restrict__ col,
                           const float* __restrict__ dis, const float* __restrict__ xw,
                           float* __restrict__ agg) {
    long long t = (long long)blockIdx.x * blockDim.x + threadIdx.x;
    const long long total = (long long)N_EDGES * F;
    if (t >= total) return;
    int e = (int)(t / F);
    int f = (int)(t % F);
    int r = row[e], c = col[e];
    float nrm = dis[r] * dis[c];
    atomicAdd(&agg[(long long)c * F + f], xw[(long long)r * F + f] * nrm);
}

// ---------------- self-loop + bias, and BN statistics ----------------
template <int F>
__global__ void post_stats_kernel(const float* __restrict__ xw, const float* __restrict__ dis,
                                  const float* __restrict__ b, float* __restrict__ agg,
                                  float* __restrict__ bn_sum, float* __restrict__ bn_sumsq) {
    __shared__ float s_sum[F];
    __shared__ float s_sq[F];
    if (threadIdx.x < F) { s_sum[threadIdx.x] = 0.f; s_sq[threadIdx.x] = 0.f; }
    __syncthreads();
    int t = blockIdx.x * blockDim.x + threadIdx.x;
    const int total = N_NODES * F;
    if (t < total) {
        int i = t / F, f = t % F;
        float d = dis[i];
        float v = agg[t] + xw[t] * d * d + b[f];
        agg[t] = v;
        atomicAdd(&s_sum[f], v);
        atomicAdd(&s_sq[f], v * v);
    }
    __syncthreads();
    if (threadIdx.x < F) {
        atomicAdd(&bn_sum[threadIdx.x], s_sum[threadIdx.x]);
        atomicAdd(&bn_sumsq[threadIdx.x], s_sq[threadIdx.x]);
    }
}

// ---------------- BN apply + ReLU ----------------
template <int F>
__global__ void bn_relu_kernel(const float* __restrict__ hpre, const float* __restrict__ bn_sum,
                               const float* __restrict__ bn_sumsq, const float* __restrict__ g,
                               const float* __restrict__ be, float* __restrict__ out) {
    int t = blockIdx.x * blockDim.x + threadIdx.x;
    const int total = N_NODES * F;
    if (t >= total) return;
    int f = t % F;
    const float invN = 1.0f / N_NODES;
    float mean = bn_sum[f] * invN;
    float var = bn_sumsq[f] * invN - mean * mean;
    float y = (hpre[t] - mean) * rsqrtf(var + BN_EPS) * g[f] + be[f];
    out[t] = y > 0.f ? y : 0.f;
}

// ---------------- mean pool ----------------
__global__ void pool_kernel(const float* __restrict__ h, const int* __restrict__ batch,
                            float* __restrict__ pooled, float* __restrict__ cnt) {
    int t = blockIdx.x * blockDim.x + threadIdx.x;
    const int total = N_NODES * 64;
    if (t >= total) return;
    int i = t >> 6, f = t & 63;
    int bb = batch[i];
    atomicAdd(&pooled[bb * 64 + f], h[t]);
    if (f == 0) atomicAdd(&cnt[bb], 1.0f);
}

// ---------------- final linear ----------------
__global__ void final_kernel(const float* __restrict__ pooled, const float* __restrict__ cnt,
                             const float* __restrict__ fcW, const float* __restrict__ fcb,
                             float* __restrict__ out) {
    int t = blockIdx.x * blockDim.x + threadIdx.x;
    if (t >= B_GRAPHS * 10) return;
    int b = t / 10, j = t % 10;
    float inv = 1.0f / fmaxf(cnt[b], 1.0f);
    float acc = fcb[j];
#pragma unroll
    for (int f = 0; f < 64; f++) acc += pooled[b * 64 + f] * inv * fcW[f * 10 + j];
    out[t] = acc;
}

static inline int cdiv(long long a, int b) { return (int)((a + b - 1) / b); }

extern "C" void kernel_launch(void* const* d_in, const int* in_sizes, int n_in,
                              void* d_out, int out_size, void* d_ws, size_t ws_size,
                              hipStream_t stream) {
    const float* x  = (const float*)d_in[0];
    const int* ei   = (const int*)d_in[1];      // [2, E] int32
    const int* batch= (const int*)d_in[2];
    const float* W1 = (const float*)d_in[3];  const float* b1 = (const float*)d_in[4];
    const float* g1 = (const float*)d_in[5];  const float* be1= (const float*)d_in[6];
    const float* W2 = (const float*)d_in[7];  const float* b2 = (const float*)d_in[8];
    const float* g2 = (const float*)d_in[9];  const float* be2= (const float*)d_in[10];
    const float* W3 = (const float*)d_in[11]; const float* b3 = (const float*)d_in[12];
    const float* g3 = (const float*)d_in[13]; const float* be3= (const float*)d_in[14];
    const float* fcW= (const float*)d_in[15]; const float* fcb= (const float*)d_in[16];
    float* out = (float*)d_out;

    const int* row = ei;
    const int* col = ei + N_EDGES;

    // workspace layout (floats)
    float* ws = (float*)d_ws;
    float* dis    = ws;                          // N
    float* P1     = ws + 100000;                 // N*64
    float* P2     = P1 + N_NODES * 64;           // N*64
    float* P3     = P2 + N_NODES * 64;           // N*64
    float* bn_sum = P3 + N_NODES * 64;           // 64
    float* bn_sq  = bn_sum + 64;                 // 64
    float* pooled = bn_sq + 64;                  // 64*64
    float* cnt    = pooled + 64 * 64;            // 64

    const int BS = 256;

    // degree -> dis
    hipMemsetAsync(dis, 0, N_NODES * sizeof(float), stream);
    deg_kernel<<<cdiv(N_EDGES, BS), BS, 0, stream>>>(col, dis);
    dis_kernel<<<cdiv(N_NODES, BS), BS, 0, stream>>>(dis);

    // ---- layer 1: x(3) -> 16.  xw=P1, agg=P2, h1=P3
    matmul_kernel<3, 16><<<cdiv((long long)N_NODES * 16, BS), BS, 0, stream>>>(x, W1, P1);
    hipMemsetAsync(P2, 0, (size_t)N_NODES * 16 * sizeof(float), stream);
    agg_kernel<16><<<cdiv((long long)N_EDGES * 16, BS), BS, 0, stream>>>(row, col, dis, P1, P2);
    hipMemsetAsync(bn_sum, 0, 128 * sizeof(float), stream);
    post_stats_kernel<16><<<cdiv((long long)N_NODES * 16, BS), BS, 0, stream>>>(P1, dis, b1, P2, bn_sum, bn_sq);
    bn_relu_kernel<16><<<cdiv((long long)N_NODES * 16, BS), BS, 0, stream>>>(P2, bn_sum, bn_sq, g1, be1, P3);

    // ---- layer 2: h1(16) -> 32.  xw=P1, agg=P2, h2=P1 (xw dead at bn time)
    matmul_kernel<16, 32><<<cdiv((long long)N_NODES * 32, BS), BS, 0, stream>>>(P3, W2, P1);
    hipMemsetAsync(P2, 0, (size_t)N_NODES * 32 * sizeof(float), stream);
    agg_kernel<32><<<cdiv((long long)N_EDGES * 32, BS), BS, 0, stream>>>(row, col, dis, P1, P2);
    hipMemsetAsync(bn_sum, 0, 128 * sizeof(float), stream);
    post_stats_kernel<32><<<cdiv((long long)N_NODES * 32, BS), BS, 0, stream>>>(P1, dis, b2, P2, bn_sum, bn_sq);
    bn_relu_kernel<32><<<cdiv((long long)N_NODES * 32, BS), BS, 0, stream>>>(P2, bn_sum, bn_sq, g2, be2, P1);

    // ---- layer 3: h2(32) -> 64.  xw=P3, agg=P2, h3=P1
    matmul_kernel<32, 64><<<cdiv((long long)N_NODES * 64, BS), BS, 0, stream>>>(P1, W3, P3);
    hipMemsetAsync(P2, 0, (size_t)N_NODES * 64 * sizeof(float), stream);
    agg_kernel<64><<<cdiv((long long)N_EDGES * 64, BS), BS, 0, stream>>>(row, col, dis, P3, P2);
    hipMemsetAsync(bn_sum, 0, 128 * sizeof(float), stream);
    post_stats_kernel<64><<<cdiv((long long)N_NODES * 64, BS), BS, 0, stream>>>(P3, dis, b3, P2, bn_sum, bn_sq);
    bn_relu_kernel<64><<<cdiv((long long)N_NODES * 64, BS), BS, 0, stream>>>(P2, bn_sum, bn_sq, g3, be3, P1);

    // ---- pool + fc
    hipMemsetAsync(pooled, 0, (64 * 64 + 64) * sizeof(float), stream);
    pool_kernel<<<cdiv((long long)N_NODES * 64, BS), BS, 0, stream>>>(P1, batch, pooled, cnt);
    final_kernel<<<1, B_GRAPHS * 10, 0, stream>>>(pooled, cnt, fcW, fcb, out);
}